// Round 3
// baseline (153.699 us; speedup 1.0000x reference)
//
#include <hip/hip_runtime.h>
#include <stdint.h>

// GPT2 attention fused pipeline, MI355X/gfx950.
// B=2, S=2048, H=768, nh=12, hd=64. fp32 I/O, bf16 internal compute (MFMA).

#define B_   2
#define S_   2048
#define H_   768
#define NH_  12
#define HD_  64
#define M_   4096      // B_*S_
#define K_   768
#define N_QKV 2304
#define QKV_ELEMS (B_*NH_*S_*HD_)   // per tensor (Q or K or V^T)
#define INF_ __builtin_inff()
#define SCL_ 0.18033688f            // (1/sqrt(64)) * log2(e)

using bf16x8 = __attribute__((ext_vector_type(8))) __bf16;
using f32x4  = __attribute__((ext_vector_type(4))) float;
using f32x16 = __attribute__((ext_vector_type(16))) float;

__device__ inline unsigned short f2bf(float f) {
  unsigned int u = __float_as_uint(f);
  u = (u + 0x7FFFu + ((u >> 16) & 1u)) >> 16;   // RNE
  return (unsigned short)u;
}
__device__ inline float fexp2(float x) {        // v_exp_f32 = 2^x
  float r; asm("v_exp_f32 %0, %1" : "=v"(r) : "v"(x)); return r;
}
__device__ inline unsigned cvtpk(float lo, float hi) {
  unsigned r; asm("v_cvt_pk_bf16_f32 %0, %1, %2" : "=v"(r) : "v"(lo), "v"(hi)); return r;
}

// ---------------- cast fp32 -> bf16 (3 tensors in one launch) ----------------
__global__ void cast3(const float* __restrict__ s0, unsigned short* __restrict__ d0, int n0f,
                      const float* __restrict__ s1, unsigned short* __restrict__ d1, int n1f,
                      const float* __restrict__ s2, unsigned short* __restrict__ d2, int n2f) {
  int i = blockIdx.x * blockDim.x + threadIdx.x;
  const float* s; unsigned short* d; int j;
  if (i < n0f)                { s = s0; d = d0; j = i; }
  else if (i < n0f + n1f)     { s = s1; d = d1; j = i - n0f; }
  else if (i < n0f + n1f + n2f) { s = s2; d = d2; j = i - n0f - n1f; }
  else return;
  float4 v = reinterpret_cast<const float4*>(s)[j];
  ushort4 o;
  o.x = f2bf(v.x); o.y = f2bf(v.y); o.z = f2bf(v.z); o.w = f2bf(v.w);
  reinterpret_cast<ushort4*>(d)[j] = o;
}

// ---------------- NT GEMM: C[m,n] = sum_k A[m,k]*Bw[n,k] + bias[n] ----------------
// MODE 0: scatter bf16 into Q (b,h,s,d), K (b,h,s,d), V^T (b,h,d,s).
// MODE 1: fp32 store to out.
template<int N, int MODE>
__global__ __launch_bounds__(256, 2)
void gemm_nt(const unsigned short* __restrict__ A,
             const unsigned short* __restrict__ Bw,
             const float* __restrict__ bias,
             unsigned short* __restrict__ qkv_base,
             float* __restrict__ outp)
{
  __shared__ unsigned short As[128*32];
  __shared__ unsigned short Bs[128*32];
  const int tid  = threadIdx.x;
  const int lane = tid & 63;
  const int wid  = tid >> 6;
  const int g = lane >> 4, lr = lane & 15;
  const int wm = wid >> 1, wn = wid & 1;
  const int n0 = blockIdx.x * 128;
  const int m0 = blockIdx.y * 128;

  f32x4 acc[4][4];
  #pragma unroll
  for (int i = 0; i < 4; ++i)
    #pragma unroll
    for (int j = 0; j < 4; ++j) acc[i][j] = f32x4{0.f, 0.f, 0.f, 0.f};

  for (int k0 = 0; k0 < K_; k0 += 32) {
    #pragma unroll
    for (int it = 0; it < 2; ++it) {
      int chunk = tid + it * 256;          // 512 chunks of 8 bf16
      int row = chunk >> 2, slot = chunk & 3;
      int sw = (slot ^ ((row >> 1) & 3)) * 8;
      *reinterpret_cast<uint4*>(&As[row*32 + sw]) =
          *reinterpret_cast<const uint4*>(&A[(size_t)(m0 + row) * K_ + k0 + slot*8]);
      *reinterpret_cast<uint4*>(&Bs[row*32 + sw]) =
          *reinterpret_cast<const uint4*>(&Bw[(size_t)(n0 + row) * K_ + k0 + slot*8]);
    }
    __syncthreads();
    bf16x8 af[4], bfr[4];
    #pragma unroll
    for (int i = 0; i < 4; ++i) {
      int ra = wm*64 + i*16 + lr;
      af[i]  = *reinterpret_cast<const bf16x8*>(&As[ra*32 + ((g ^ ((ra>>1)&3))*8)]);
      int rb = wn*64 + i*16 + lr;
      bfr[i] = *reinterpret_cast<const bf16x8*>(&Bs[rb*32 + ((g ^ ((rb>>1)&3))*8)]);
    }
    #pragma unroll
    for (int i = 0; i < 4; ++i)
      #pragma unroll
      for (int j = 0; j < 4; ++j)
        acc[i][j] = __builtin_amdgcn_mfma_f32_16x16x32_bf16(af[i], bfr[j], acc[i][j], 0, 0, 0);
    __syncthreads();
  }

  // epilogue: C row = m0+wm*64+i*16+g*4+r, col = n0+wn*64+j*16+lr  (m89 layout)
  #pragma unroll
  for (int j = 0; j < 4; ++j) {
    int col = n0 + wn*64 + j*16 + lr;
    float bv = bias[col];
    if constexpr (MODE == 0) {
      int which = col / 768;               // 0=Q 1=K 2=V (frag never crosses boundary)
      int rem = col - which * 768;
      int h = rem >> 6, d = rem & 63;
      if (which < 2) {
        unsigned short* dst = qkv_base + (size_t)which * QKV_ELEMS;
        #pragma unroll
        for (int i = 0; i < 4; ++i)
          #pragma unroll
          for (int r = 0; r < 4; ++r) {
            int rowm = m0 + wm*64 + i*16 + g*4 + r;
            int bb = rowm >> 11, ss = rowm & 2047;
            dst[(((size_t)(bb*NH_ + h))*S_ + ss)*HD_ + d] = f2bf(acc[i][j][r] + bv);
          }
      } else {
        // V stored TRANSPOSED per head: (b,h,d,s); 4 consecutive s -> 8B store
        unsigned short* dst = qkv_base + 2*(size_t)QKV_ELEMS;
        #pragma unroll
        for (int i = 0; i < 4; ++i) {
          int rowm = m0 + wm*64 + i*16 + g*4;
          int bb = rowm >> 11, ss = rowm & 2047;
          unsigned w0 = (unsigned)f2bf(acc[i][j][0] + bv) | ((unsigned)f2bf(acc[i][j][1] + bv) << 16);
          unsigned w1 = (unsigned)f2bf(acc[i][j][2] + bv) | ((unsigned)f2bf(acc[i][j][3] + bv) << 16);
          uint2 u; u.x = w0; u.y = w1;
          *reinterpret_cast<uint2*>(&dst[(((size_t)(bb*NH_ + h))*HD_ + d)*S_ + ss]) = u;
        }
      }
    } else {
      #pragma unroll
      for (int i = 0; i < 4; ++i)
        #pragma unroll
        for (int r = 0; r < 4; ++r) {
          int rowm = m0 + wm*64 + i*16 + g*4 + r;
          outp[(size_t)rowm * H_ + col] = acc[i][j][r] + bv;
        }
    }
  }
}

// ---------------- flash attention (causal), barrier-free streaming ----------------
// Block = 2 waves, one q-tile of 32 rows. Wave w handles kv tiles t === w (mod 2)
// (32-wide tiles), keeping private (m,l,O^T); merged once at the end via LDS.
// K and V^T are read DIRECTLY from global (L2-resident per head via XCD-locked
// block mapping: blockIdx%8 == bh%8). S^T = K.Q^T makes softmax lane-local;
// P^T B-frags built in-register via v_cvt_pk_bf16_f32 + v_permlane32_swap_b32.
// No __syncthreads in the main loop.
__global__ __launch_bounds__(128, 3)
void attn_fwd(const unsigned short* __restrict__ Qp,
              const unsigned short* __restrict__ Kp,
              const unsigned short* __restrict__ Vtp,
              unsigned short* __restrict__ attn)
{
  __shared__ float Osc[2][64*33];     // [wave][d*33 + q]  (stride 33: 2-way banks)
  __shared__ float mlb[2][64];        // [wave][{m[32], l[32]}]

  const int tid = threadIdx.x;
  const int l = tid & 63, w = tid >> 6;
  const int q31 = l & 31, hi = l >> 5;
  // XCD-locked decode: idx%8 == bh%8 (3 heads per XCD -> K+V^T 1.5MB, L2-fits).
  const int idx = blockIdx.x;
  const int bh = (idx & 7) + 8 * ((idx >> 3) % 3);
  const int qo = (idx >> 3) / 3;
  const int qt = 63 - qo;             // heavy q-tiles dispatched first
  const int qrow = qt*32 + q31;

  const unsigned short* Qh  = Qp  + (size_t)bh * S_ * HD_;
  const unsigned short* Kh  = Kp  + (size_t)bh * S_ * HD_;
  const unsigned short* Vth = Vtp + (size_t)bh * HD_ * S_;

  // Q B-frags (col = q31, k = d)
  bf16x8 qf[4];
  #pragma unroll
  for (int ks = 0; ks < 4; ++ks)
    qf[ks] = *reinterpret_cast<const bf16x8*>(&Qh[(size_t)qrow*HD_ + ks*16 + hi*8]);

  f32x16 oacc[2];
  #pragma unroll
  for (int m2 = 0; m2 < 2; ++m2)
    #pragma unroll
    for (int r = 0; r < 16; ++r) oacc[m2][r] = 0.f;
  float mrun = -INF_, lrun = 0.f;

  const int p = w;                                   // kv-tile parity
  const int nt = (qt >= p) ? ((qt - p) >> 1) + 1 : 0;
  const bool hasDiag = ((qt & 1) == p);

  // per-lane streaming pointers (advance by 64 kv per iteration = 2 tiles)
  const unsigned short* kptr  = Kh  + (size_t)(p*32 + q31)*HD_ + hi*8;
  const unsigned short* vptr0 = Vth + (size_t)q31*S_      + p*32 + hi*8;
  const unsigned short* vptr1 = Vth + (size_t)(32+q31)*S_ + p*32 + hi*8;

  uint4 kb[2][4], vb[4];
  if (nt > 0) {
    #pragma unroll
    for (int ks = 0; ks < 4; ++ks)
      kb[0][ks] = *reinterpret_cast<const uint4*>(kptr + ks*16);
  }
  int cur = 0;
  for (int i = 0; i < nt; ++i) {
    // V^T A-frags for THIS tile (used late in the step -> latency self-hides)
    vb[0] = *reinterpret_cast<const uint4*>(vptr0);
    vb[1] = *reinterpret_cast<const uint4*>(vptr0 + 16);
    vb[2] = *reinterpret_cast<const uint4*>(vptr1);
    vb[3] = *reinterpret_cast<const uint4*>(vptr1 + 16);
    vptr0 += 64; vptr1 += 64;
    // K prefetch for NEXT tile
    if (i + 1 < nt) {
      kptr += 64*HD_;
      #pragma unroll
      for (int ks = 0; ks < 4; ++ks)
        kb[cur^1][ks] = *reinterpret_cast<const uint4*>(kptr + ks*16);
    }

    // ---- S^T = K . Q^T (32 kv x 32 q) ----
    f32x16 sf;
    #pragma unroll
    for (int r = 0; r < 16; ++r) sf[r] = 0.f;
    __builtin_amdgcn_s_setprio(1);
    #pragma unroll
    for (int ks = 0; ks < 4; ++ks)
      sf = __builtin_amdgcn_mfma_f32_32x32x16_bf16(
          *reinterpret_cast<bf16x8*>(&kb[cur][ks]), qf[ks], sf, 0, 0, 0);
    __builtin_amdgcn_s_setprio(0);

    // ---- causal mask (diag tile only) ----
    if (hasDiag && i == nt - 1) {
      const int kv0 = qt*32;
      #pragma unroll
      for (int r = 0; r < 16; ++r) {
        int kv = kv0 + (r & 3) + 8*(r >> 2) + 4*hi;
        if (kv > qrow) sf[r] = -1e38f;
      }
    }

    // ---- lane-local online softmax (exp2 domain), defer-max (THR=8) ----
    float mtr = sf[0];
    #pragma unroll
    for (int r = 1; r < 16; ++r) mtr = fmaxf(mtr, sf[r]);
    mtr = fmaxf(mtr, __shfl_xor(mtr, 32));
    float mt = mtr * SCL_;
    float corr = 1.f;
    if (__any(mt > mrun + 8.0f)) {
      float mnew = fmaxf(mrun, mt);
      corr = fexp2(mrun - mnew);
      mrun = mnew;
      #pragma unroll
      for (int m2 = 0; m2 < 2; ++m2)
        #pragma unroll
        for (int r = 0; r < 16; ++r) oacc[m2][r] *= corr;
    }
    float rs = 0.f;
    #pragma unroll
    for (int r = 0; r < 16; ++r) {
      sf[r] = fexp2(fmaf(sf[r], SCL_, -mrun));
      rs += sf[r];
    }
    rs += __shfl_xor(rs, 32);
    lrun = fmaf(lrun, corr, rs);

    // ---- P^T B-frags in-register: cvt_pk pairs + permlane32_swap ----
    unsigned pw[8];
    #pragma unroll
    for (int q4 = 0; q4 < 8; ++q4) pw[q4] = cvtpk(sf[2*q4], sf[2*q4 + 1]);
    asm("v_permlane32_swap_b32 %0, %1" : "+v"(pw[0]), "+v"(pw[2]));
    asm("v_permlane32_swap_b32 %0, %1" : "+v"(pw[1]), "+v"(pw[3]));
    asm("v_permlane32_swap_b32 %0, %1" : "+v"(pw[4]), "+v"(pw[6]));
    asm("v_permlane32_swap_b32 %0, %1" : "+v"(pw[5]), "+v"(pw[7]));
    uint4 pf0; pf0.x = pw[0]; pf0.y = pw[1]; pf0.z = pw[2]; pf0.w = pw[3];
    uint4 pf1; pf1.x = pw[4]; pf1.y = pw[5]; pf1.z = pw[6]; pf1.w = pw[7];

    // ---- O^T += V^T . P^T ----
    __builtin_amdgcn_s_setprio(1);
    oacc[0] = __builtin_amdgcn_mfma_f32_32x32x16_bf16(
        *reinterpret_cast<bf16x8*>(&vb[0]), *reinterpret_cast<bf16x8*>(&pf0), oacc[0], 0, 0, 0);
    oacc[0] = __builtin_amdgcn_mfma_f32_32x32x16_bf16(
        *reinterpret_cast<bf16x8*>(&vb[1]), *reinterpret_cast<bf16x8*>(&pf1), oacc[0], 0, 0, 0);
    oacc[1] = __builtin_amdgcn_mfma_f32_32x32x16_bf16(
        *reinterpret_cast<bf16x8*>(&vb[2]), *reinterpret_cast<bf16x8*>(&pf0), oacc[1], 0, 0, 0);
    oacc[1] = __builtin_amdgcn_mfma_f32_32x32x16_bf16(
        *reinterpret_cast<bf16x8*>(&vb[3]), *reinterpret_cast<bf16x8*>(&pf1), oacc[1], 0, 0, 0);
    __builtin_amdgcn_s_setprio(0);

    cur ^= 1;
  }

  // ---- write partial O^T + (m,l); merge the 2 waves; store bf16 ----
  #pragma unroll
  for (int m2 = 0; m2 < 2; ++m2)
    #pragma unroll
    for (int r = 0; r < 16; ++r) {
      int d = m2*32 + (r & 3) + 8*(r >> 2) + 4*hi;
      Osc[w][d*33 + q31] = oacc[m2][r];
    }
  if (l < 32) { mlb[w][q31] = mrun; mlb[w][32 + q31] = lrun; }
  __syncthreads();

  {
    const int q = tid & 31, dseg = tid >> 5;          // 4 dsegs x 16 d
    const int bb = bh / NH_, hh = bh % NH_;
    float m0 = mlb[0][q], l0 = mlb[0][32 + q];
    float m1 = mlb[1][q], l1 = mlb[1][32 + q];
    float M  = fmaxf(m0, m1);
    float e0 = fexp2(m0 - M), e1 = fexp2(m1 - M);     // -inf -> 0
    float inv = 1.f / (l0*e0 + l1*e1);
    unsigned ow[8];
    #pragma unroll
    for (int k2 = 0; k2 < 8; ++k2) {
      int d0 = dseg*16 + k2*2;
      float a = (Osc[0][d0*33 + q]*e0 + Osc[1][d0*33 + q]*e1) * inv;
      float b = (Osc[0][(d0+1)*33 + q]*e0 + Osc[1][(d0+1)*33 + q]*e1) * inv;
      ow[k2] = cvtpk(a, b);
    }
    unsigned short* dst = &attn[((size_t)(bb*S_ + qt*32 + q))*H_ + hh*HD_ + dseg*16];
    uint4 o0; o0.x = ow[0]; o0.y = ow[1]; o0.z = ow[2]; o0.w = ow[3];
    uint4 o1; o1.x = ow[4]; o1.y = ow[5]; o1.z = ow[6]; o1.w = ow[7];
    *reinterpret_cast<uint4*>(dst)     = o0;
    *reinterpret_cast<uint4*>(dst + 8) = o1;
  }
}

// ---------------- launch ----------------
extern "C" void kernel_launch(void* const* d_in, const int* in_sizes, int n_in,
                              void* d_out, int out_size, void* d_ws, size_t ws_size,
                              hipStream_t stream)
{
  const float* x      = (const float*)d_in[0];
  const float* w_qkv  = (const float*)d_in[1];
  const float* b_qkv  = (const float*)d_in[2];
  const float* w_o    = (const float*)d_in[3];
  const float* b_o    = (const float*)d_in[4];
  float* out = (float*)d_out;

  unsigned short* xb    = (unsigned short*)d_ws;          // 4096x768
  unsigned short* wqkvb = xb    + (size_t)M_ * K_;        // 2304x768
  unsigned short* wob   = wqkvb + (size_t)N_QKV * K_;     // 768x768
  unsigned short* Qw    = wob   + (size_t)H_ * H_;        // (b,h,s,d)
  unsigned short* Kw    = Qw + (size_t)QKV_ELEMS;         // (b,h,s,d)
  unsigned short* Vtw   = Kw + (size_t)QKV_ELEMS;         // (b,h,d,s)  TRANSPOSED
  unsigned short* attn  = Vtw + (size_t)QKV_ELEMS;        // 4096x768

  cast3<<<5376, 256, 0, stream>>>(x, xb, 786432,
                                  w_qkv, wqkvb, 442368,
                                  w_o, wob, 147456);
  gemm_nt<N_QKV, 0><<<dim3(18, 32), 256, 0, stream>>>(xb, wqkvb, b_qkv, Qw, nullptr);
  attn_fwd<<<dim3(1536), 128, 0, stream>>>(Qw, Kw, Vtw, attn);
  gemm_nt<H_, 1><<<dim3(6, 32), 256, 0, stream>>>(attn, wob, b_o, nullptr, out);
}

// Round 4
// 112.484 us; speedup vs baseline: 1.3664x; 1.3664x over previous
//
#include <hip/hip_runtime.h>
#include <stdint.h>

// GPT2 attention fused pipeline, MI355X/gfx950.
// B=2, S=2048, H=768, nh=12, hd=64. fp32 I/O, bf16 internal compute (MFMA).

#define B_   2
#define S_   2048
#define H_   768
#define NH_  12
#define HD_  64
#define M_   4096      // B_*S_
#define K_   768
#define N_QKV 2304
#define QKV_ELEMS (B_*NH_*S_*HD_)   // per tensor (Q or K or V^T)
#define INF_ __builtin_inff()
#define SCL_ 0.18033688f            // (1/sqrt(64)) * log2(e)

using bf16x8 = __attribute__((ext_vector_type(8))) __bf16;
using f32x4  = __attribute__((ext_vector_type(4))) float;
using f32x16 = __attribute__((ext_vector_type(16))) float;

__device__ inline unsigned short f2bf(float f) {
  unsigned int u = __float_as_uint(f);
  u = (u + 0x7FFFu + ((u >> 16) & 1u)) >> 16;   // RNE
  return (unsigned short)u;
}
__device__ inline float fexp2(float x) {        // v_exp_f32 = 2^x
  float r; asm("v_exp_f32 %0, %1" : "=v"(r) : "v"(x)); return r;
}
__device__ inline unsigned cvtpk(float lo, float hi) {
  unsigned r; asm("v_cvt_pk_bf16_f32 %0, %1, %2" : "=v"(r) : "v"(lo), "v"(hi)); return r;
}

// ---------------- cast fp32 -> bf16 (3 tensors in one launch) ----------------
__global__ void cast3(const float* __restrict__ s0, unsigned short* __restrict__ d0, int n0f,
                      const float* __restrict__ s1, unsigned short* __restrict__ d1, int n1f,
                      const float* __restrict__ s2, unsigned short* __restrict__ d2, int n2f) {
  int i = blockIdx.x * blockDim.x + threadIdx.x;
  const float* s; unsigned short* d; int j;
  if (i < n0f)                { s = s0; d = d0; j = i; }
  else if (i < n0f + n1f)     { s = s1; d = d1; j = i - n0f; }
  else if (i < n0f + n1f + n2f) { s = s2; d = d2; j = i - n0f - n1f; }
  else return;
  float4 v = reinterpret_cast<const float4*>(s)[j];
  ushort4 o;
  o.x = f2bf(v.x); o.y = f2bf(v.y); o.z = f2bf(v.z); o.w = f2bf(v.w);
  reinterpret_cast<ushort4*>(d)[j] = o;
}

// ---------------- NT GEMM: C[m,n] = sum_k A[m,k]*Bw[n,k] + bias[n] ----------------
// MODE 0: scatter bf16 into Q (b,h,s,d), K (b,h,s,d), V^T (b,h,d,s).
// MODE 1: fp32 store to out.
template<int N, int MODE>
__global__ __launch_bounds__(256, 2)
void gemm_nt(const unsigned short* __restrict__ A,
             const unsigned short* __restrict__ Bw,
             const float* __restrict__ bias,
             unsigned short* __restrict__ qkv_base,
             float* __restrict__ outp)
{
  __shared__ unsigned short As[128*32];
  __shared__ unsigned short Bs[128*32];
  const int tid  = threadIdx.x;
  const int lane = tid & 63;
  const int wid  = tid >> 6;
  const int g = lane >> 4, lr = lane & 15;
  const int wm = wid >> 1, wn = wid & 1;
  const int n0 = blockIdx.x * 128;
  const int m0 = blockIdx.y * 128;

  f32x4 acc[4][4];
  #pragma unroll
  for (int i = 0; i < 4; ++i)
    #pragma unroll
    for (int j = 0; j < 4; ++j) acc[i][j] = f32x4{0.f, 0.f, 0.f, 0.f};

  for (int k0 = 0; k0 < K_; k0 += 32) {
    #pragma unroll
    for (int it = 0; it < 2; ++it) {
      int chunk = tid + it * 256;          // 512 chunks of 8 bf16
      int row = chunk >> 2, slot = chunk & 3;
      int sw = (slot ^ ((row >> 1) & 3)) * 8;
      *reinterpret_cast<uint4*>(&As[row*32 + sw]) =
          *reinterpret_cast<const uint4*>(&A[(size_t)(m0 + row) * K_ + k0 + slot*8]);
      *reinterpret_cast<uint4*>(&Bs[row*32 + sw]) =
          *reinterpret_cast<const uint4*>(&Bw[(size_t)(n0 + row) * K_ + k0 + slot*8]);
    }
    __syncthreads();
    bf16x8 af[4], bfr[4];
    #pragma unroll
    for (int i = 0; i < 4; ++i) {
      int ra = wm*64 + i*16 + lr;
      af[i]  = *reinterpret_cast<const bf16x8*>(&As[ra*32 + ((g ^ ((ra>>1)&3))*8)]);
      int rb = wn*64 + i*16 + lr;
      bfr[i] = *reinterpret_cast<const bf16x8*>(&Bs[rb*32 + ((g ^ ((rb>>1)&3))*8)]);
    }
    #pragma unroll
    for (int i = 0; i < 4; ++i)
      #pragma unroll
      for (int j = 0; j < 4; ++j)
        acc[i][j] = __builtin_amdgcn_mfma_f32_16x16x32_bf16(af[i], bfr[j], acc[i][j], 0, 0, 0);
    __syncthreads();
  }

  // epilogue: C row = m0+wm*64+i*16+g*4+r, col = n0+wn*64+j*16+lr  (m89 layout)
  #pragma unroll
  for (int j = 0; j < 4; ++j) {
    int col = n0 + wn*64 + j*16 + lr;
    float bv = bias[col];
    if constexpr (MODE == 0) {
      int which = col / 768;               // 0=Q 1=K 2=V (frag never crosses boundary)
      int rem = col - which * 768;
      int h = rem >> 6, d = rem & 63;
      if (which < 2) {
        unsigned short* dst = qkv_base + (size_t)which * QKV_ELEMS;
        #pragma unroll
        for (int i = 0; i < 4; ++i)
          #pragma unroll
          for (int r = 0; r < 4; ++r) {
            int rowm = m0 + wm*64 + i*16 + g*4 + r;
            int bb = rowm >> 11, ss = rowm & 2047;
            dst[(((size_t)(bb*NH_ + h))*S_ + ss)*HD_ + d] = f2bf(acc[i][j][r] + bv);
          }
      } else {
        // V stored TRANSPOSED per head: (b,h,d,s); 4 consecutive s -> 8B store
        unsigned short* dst = qkv_base + 2*(size_t)QKV_ELEMS;
        #pragma unroll
        for (int i = 0; i < 4; ++i) {
          int rowm = m0 + wm*64 + i*16 + g*4;
          int bb = rowm >> 11, ss = rowm & 2047;
          unsigned w0 = (unsigned)f2bf(acc[i][j][0] + bv) | ((unsigned)f2bf(acc[i][j][1] + bv) << 16);
          unsigned w1 = (unsigned)f2bf(acc[i][j][2] + bv) | ((unsigned)f2bf(acc[i][j][3] + bv) << 16);
          uint2 u; u.x = w0; u.y = w1;
          *reinterpret_cast<uint2*>(&dst[(((size_t)(bb*NH_ + h))*HD_ + d)*S_ + ss]) = u;
        }
      }
    } else {
      #pragma unroll
      for (int i = 0; i < 4; ++i)
        #pragma unroll
        for (int r = 0; r < 4; ++r) {
          int rowm = m0 + wm*64 + i*16 + g*4 + r;
          outp[(size_t)rowm * H_ + col] = acc[i][j][r] + bv;
        }
    }
  }
}

// ---------------- flash attention (causal), barrier-free streaming ----------------
// Block = 4 waves, one q-tile of 32 rows. Wave w handles kv tiles t === w (mod 4),
// keeping private (m,l,O^T); 4-way merge at the end via LDS.
// K and V^T read DIRECTLY from global (L2-resident per head via XCD-locked
// block mapping: blockIdx%8 == bh%8). S^T = K.Q^T makes softmax lane-local;
// P^T B-frags built in-register via v_cvt_pk_bf16_f32 + v_permlane32_swap_b32.
// All register buffers statically indexed (no runtime-indexed arrays -> no scratch).
__global__ __launch_bounds__(256, 4)
void attn_fwd(const unsigned short* __restrict__ Qp,
              const unsigned short* __restrict__ Kp,
              const unsigned short* __restrict__ Vtp,
              unsigned short* __restrict__ attn)
{
  __shared__ float Osc[4][32*68];     // [wave][q*68 + d]  (stride 68: 16B-aligned rows)
  __shared__ float mlb[4][64];        // [wave][{m[32], l[32]}]

  const int tid = threadIdx.x;
  const int l = tid & 63, w = tid >> 6;
  const int q31 = l & 31, hi = l >> 5;
  // XCD-locked decode: idx%8 == bh%8 (3 heads per XCD -> K+V^T 1.5MB, L2-fits).
  const int idx = blockIdx.x;
  const int bh = (idx & 7) + 8 * ((idx >> 3) % 3);
  const int qo = (idx >> 3) / 3;
  const int qt = 63 - qo;             // heavy q-tiles dispatched first
  const int qrow = qt*32 + q31;

  const unsigned short* Qh  = Qp  + (size_t)bh * S_ * HD_;
  const unsigned short* Kh  = Kp  + (size_t)bh * S_ * HD_;
  const unsigned short* Vth = Vtp + (size_t)bh * HD_ * S_;

  // Q B-frags (col = q31, k = d)
  bf16x8 qf[4];
  #pragma unroll
  for (int ks = 0; ks < 4; ++ks)
    qf[ks] = *reinterpret_cast<const bf16x8*>(&Qh[(size_t)qrow*HD_ + ks*16 + hi*8]);

  f32x16 oacc0, oacc1;
  #pragma unroll
  for (int r = 0; r < 16; ++r) { oacc0[r] = 0.f; oacc1[r] = 0.f; }
  float mrun = -INF_, lrun = 0.f;

  const int p = w;                                   // kv-tile residue (mod 4)
  const int nt = (qt >= p) ? ((qt - p) >> 2) + 1 : 0;
  const bool dw = ((qt & 3) == p);                   // this wave owns the diag tile
  const int ntm1 = nt - 1;

  // per-lane streaming pointers (advance by 128 kv per owned tile)
  const unsigned short* kptr  = Kh  + (size_t)(p*32 + q31)*HD_ + hi*8;
  const unsigned short* vptr0 = Vth + (size_t)q31*S_      + p*32 + hi*8;
  const unsigned short* vptr1 = Vth + (size_t)(32+q31)*S_ + p*32 + hi*8;

  uint4 kbA[4], kbB[4], vb[4];

  auto LOADK = [&](uint4 (&kb)[4]) {
    #pragma unroll
    for (int ks = 0; ks < 4; ++ks)
      kb[ks] = *reinterpret_cast<const uint4*>(kptr + ks*16);
  };
  auto LOADV = [&]() {
    vb[0] = *reinterpret_cast<const uint4*>(vptr0);
    vb[1] = *reinterpret_cast<const uint4*>(vptr0 + 16);
    vb[2] = *reinterpret_cast<const uint4*>(vptr1);
    vb[3] = *reinterpret_cast<const uint4*>(vptr1 + 16);
    vptr0 += 128; vptr1 += 128;
  };
  auto STEP = [&](uint4 (&kb)[4], int i) {
    // ---- S^T = K . Q^T (32 kv x 32 q) ----
    f32x16 sf;
    #pragma unroll
    for (int r = 0; r < 16; ++r) sf[r] = 0.f;
    __builtin_amdgcn_s_setprio(1);
    #pragma unroll
    for (int ks = 0; ks < 4; ++ks)
      sf = __builtin_amdgcn_mfma_f32_32x32x16_bf16(
          *reinterpret_cast<bf16x8*>(&kb[ks]), qf[ks], sf, 0, 0, 0);
    __builtin_amdgcn_s_setprio(0);

    // ---- causal mask (diag tile only; it is this wave's last step) ----
    if (dw && i == ntm1) {
      const int kv0 = qt*32;
      #pragma unroll
      for (int r = 0; r < 16; ++r) {
        int kv = kv0 + (r & 3) + 8*(r >> 2) + 4*hi;
        if (kv > qrow) sf[r] = -1e38f;
      }
    }

    // ---- lane-local online softmax (exp2 domain), defer-max (THR=8) ----
    float mtr = sf[0];
    #pragma unroll
    for (int r = 1; r < 16; ++r) mtr = fmaxf(mtr, sf[r]);
    mtr = fmaxf(mtr, __shfl_xor(mtr, 32));
    float mt = mtr * SCL_;
    float corr = 1.f;
    if (__any(mt > mrun + 8.0f)) {
      float mnew = fmaxf(mrun, mt);
      corr = fexp2(mrun - mnew);
      mrun = mnew;
      #pragma unroll
      for (int r = 0; r < 16; ++r) { oacc0[r] *= corr; oacc1[r] *= corr; }
    }
    float rs = 0.f;
    #pragma unroll
    for (int r = 0; r < 16; ++r) {
      sf[r] = fexp2(fmaf(sf[r], SCL_, -mrun));
      rs += sf[r];
    }
    rs += __shfl_xor(rs, 32);
    lrun = fmaf(lrun, corr, rs);

    // ---- P^T B-frags in-register: cvt_pk pairs + permlane32_swap ----
    unsigned pw0 = cvtpk(sf[0],  sf[1]);
    unsigned pw1 = cvtpk(sf[2],  sf[3]);
    unsigned pw2 = cvtpk(sf[4],  sf[5]);
    unsigned pw3 = cvtpk(sf[6],  sf[7]);
    unsigned pw4 = cvtpk(sf[8],  sf[9]);
    unsigned pw5 = cvtpk(sf[10], sf[11]);
    unsigned pw6 = cvtpk(sf[12], sf[13]);
    unsigned pw7 = cvtpk(sf[14], sf[15]);
    asm("v_permlane32_swap_b32 %0, %1" : "+v"(pw0), "+v"(pw2));
    asm("v_permlane32_swap_b32 %0, %1" : "+v"(pw1), "+v"(pw3));
    asm("v_permlane32_swap_b32 %0, %1" : "+v"(pw4), "+v"(pw6));
    asm("v_permlane32_swap_b32 %0, %1" : "+v"(pw5), "+v"(pw7));
    uint4 pf0; pf0.x = pw0; pf0.y = pw1; pf0.z = pw2; pf0.w = pw3;
    uint4 pf1; pf1.x = pw4; pf1.y = pw5; pf1.z = pw6; pf1.w = pw7;

    // ---- O^T += V^T . P^T ----
    __builtin_amdgcn_s_setprio(1);
    oacc0 = __builtin_amdgcn_mfma_f32_32x32x16_bf16(
        *reinterpret_cast<bf16x8*>(&vb[0]), *reinterpret_cast<bf16x8*>(&pf0), oacc0, 0, 0, 0);
    oacc0 = __builtin_amdgcn_mfma_f32_32x32x16_bf16(
        *reinterpret_cast<bf16x8*>(&vb[1]), *reinterpret_cast<bf16x8*>(&pf1), oacc0, 0, 0, 0);
    oacc1 = __builtin_amdgcn_mfma_f32_32x32x16_bf16(
        *reinterpret_cast<bf16x8*>(&vb[2]), *reinterpret_cast<bf16x8*>(&pf0), oacc1, 0, 0, 0);
    oacc1 = __builtin_amdgcn_mfma_f32_32x32x16_bf16(
        *reinterpret_cast<bf16x8*>(&vb[3]), *reinterpret_cast<bf16x8*>(&pf1), oacc1, 0, 0, 0);
    __builtin_amdgcn_s_setprio(0);
  };

  // ---- main loop: static ping-pong (kbA/kbB), V single-buffered ----
  if (nt > 0) LOADK(kbA);
  int i = 0;
  for (; i + 2 <= nt; i += 2) {
    LOADV();
    kptr += 128*HD_; LOADK(kbB);
    STEP(kbA, i);
    LOADV();
    if (i + 2 < nt) { kptr += 128*HD_; LOADK(kbA); }
    STEP(kbB, i + 1);
  }
  if (i < nt) { LOADV(); STEP(kbA, i); }

  // ---- write partial O^T (q-major) + (m,l); merge the 4 waves; store bf16 ----
  #pragma unroll
  for (int rr = 0; rr < 4; ++rr) {
    f32x4 a, b;
    #pragma unroll
    for (int e = 0; e < 4; ++e) { a[e] = oacc0[4*rr + e]; b[e] = oacc1[4*rr + e]; }
    *reinterpret_cast<f32x4*>(&Osc[w][q31*68 +      8*rr + 4*hi]) = a;
    *reinterpret_cast<f32x4*>(&Osc[w][q31*68 + 32 + 8*rr + 4*hi]) = b;
  }
  if (hi == 0) { mlb[w][q31] = mrun; mlb[w][32 + q31] = lrun; }
  __syncthreads();

  {
    const int q = tid & 31, dseg = (tid >> 5) & 7;    // 8 dsegs x 8 d
    const int bb = bh / NH_, hh = bh % NH_;
    float m0 = mlb[0][q], m1 = mlb[1][q], m2 = mlb[2][q], m3 = mlb[3][q];
    float l0 = mlb[0][32+q], l1 = mlb[1][32+q], l2 = mlb[2][32+q], l3 = mlb[3][32+q];
    float M = fmaxf(fmaxf(m0, m1), fmaxf(m2, m3));
    float e0 = fexp2(m0 - M), e1 = fexp2(m1 - M), e2 = fexp2(m2 - M), e3 = fexp2(m3 - M);
    float inv = 1.f / (l0*e0 + l1*e1 + l2*e2 + l3*e3);
    f32x4 a0 = *reinterpret_cast<f32x4*>(&Osc[0][q*68 + dseg*8]);
    f32x4 b0 = *reinterpret_cast<f32x4*>(&Osc[0][q*68 + dseg*8 + 4]);
    f32x4 a1 = *reinterpret_cast<f32x4*>(&Osc[1][q*68 + dseg*8]);
    f32x4 b1 = *reinterpret_cast<f32x4*>(&Osc[1][q*68 + dseg*8 + 4]);
    f32x4 a2 = *reinterpret_cast<f32x4*>(&Osc[2][q*68 + dseg*8]);
    f32x4 b2 = *reinterpret_cast<f32x4*>(&Osc[2][q*68 + dseg*8 + 4]);
    f32x4 a3 = *reinterpret_cast<f32x4*>(&Osc[3][q*68 + dseg*8]);
    f32x4 b3 = *reinterpret_cast<f32x4*>(&Osc[3][q*68 + dseg*8 + 4]);
    f32x4 ra, rb;
    #pragma unroll
    for (int e = 0; e < 4; ++e) {
      ra[e] = (a0[e]*e0 + a1[e]*e1 + a2[e]*e2 + a3[e]*e3) * inv;
      rb[e] = (b0[e]*e0 + b1[e]*e1 + b2[e]*e2 + b3[e]*e3) * inv;
    }
    uint4 ov;
    ov.x = cvtpk(ra[0], ra[1]); ov.y = cvtpk(ra[2], ra[3]);
    ov.z = cvtpk(rb[0], rb[1]); ov.w = cvtpk(rb[2], rb[3]);
    *reinterpret_cast<uint4*>(&attn[((size_t)(bb*S_ + qt*32 + q))*H_ + hh*HD_ + dseg*8]) = ov;
  }
}

// ---------------- launch ----------------
extern "C" void kernel_launch(void* const* d_in, const int* in_sizes, int n_in,
                              void* d_out, int out_size, void* d_ws, size_t ws_size,
                              hipStream_t stream)
{
  const float* x      = (const float*)d_in[0];
  const float* w_qkv  = (const float*)d_in[1];
  const float* b_qkv  = (const float*)d_in[2];
  const float* w_o    = (const float*)d_in[3];
  const float* b_o    = (const float*)d_in[4];
  float* out = (float*)d_out;

  unsigned short* xb    = (unsigned short*)d_ws;          // 4096x768
  unsigned short* wqkvb = xb    + (size_t)M_ * K_;        // 2304x768
  unsigned short* wob   = wqkvb + (size_t)N_QKV * K_;     // 768x768
  unsigned short* Qw    = wob   + (size_t)H_ * H_;        // (b,h,s,d)
  unsigned short* Kw    = Qw + (size_t)QKV_ELEMS;         // (b,h,s,d)
  unsigned short* Vtw   = Kw + (size_t)QKV_ELEMS;         // (b,h,d,s)  TRANSPOSED
  unsigned short* attn  = Vtw + (size_t)QKV_ELEMS;        // 4096x768

  cast3<<<5376, 256, 0, stream>>>(x, xb, 786432,
                                  w_qkv, wqkvb, 442368,
                                  w_o, wob, 147456);
  gemm_nt<N_QKV, 0><<<dim3(18, 32), 256, 0, stream>>>(xb, wqkvb, b_qkv, Qw, nullptr);
  attn_fwd<<<dim3(1536), 256, 0, stream>>>(Qw, Kw, Vtw, attn);
  gemm_nt<H_, 1><<<dim3(6, 32), 256, 0, stream>>>(attn, wob, b_o, nullptr, out);
}

// Round 5
// 111.721 us; speedup vs baseline: 1.3757x; 1.0068x over previous
//
#include <hip/hip_runtime.h>
#include <stdint.h>

// GPT2 attention fused pipeline, MI355X/gfx950.
// B=2, S=2048, H=768, nh=12, hd=64. fp32 I/O, bf16 internal compute (MFMA).

#define B_   2
#define S_   2048
#define H_   768
#define NH_  12
#define HD_  64
#define M_   4096      // B_*S_
#define K_   768
#define N_QKV 2304
#define QKV_ELEMS (B_*NH_*S_*HD_)   // per tensor (Q or K or V^T)
#define INF_ __builtin_inff()
#define SCL_ 0.18033688f            // (1/sqrt(64)) * log2(e)

using bf16x8 = __attribute__((ext_vector_type(8))) __bf16;
using f32x4  = __attribute__((ext_vector_type(4))) float;
using f32x16 = __attribute__((ext_vector_type(16))) float;

__device__ inline unsigned short f2bf(float f) {
  unsigned int u = __float_as_uint(f);
  u = (u + 0x7FFFu + ((u >> 16) & 1u)) >> 16;   // RNE
  return (unsigned short)u;
}
__device__ inline float fexp2(float x) {        // v_exp_f32 = 2^x
  float r; asm("v_exp_f32 %0, %1" : "=v"(r) : "v"(x)); return r;
}
__device__ inline unsigned cvtpk(float lo, float hi) {
  unsigned r; asm("v_cvt_pk_bf16_f32 %0, %1, %2" : "=v"(r) : "v"(lo), "v"(hi)); return r;
}

// ---------------- cast fp32 -> bf16 (3 tensors in one launch) ----------------
__global__ void cast3(const float* __restrict__ s0, unsigned short* __restrict__ d0, int n0f,
                      const float* __restrict__ s1, unsigned short* __restrict__ d1, int n1f,
                      const float* __restrict__ s2, unsigned short* __restrict__ d2, int n2f) {
  int i = blockIdx.x * blockDim.x + threadIdx.x;
  const float* s; unsigned short* d; int j;
  if (i < n0f)                { s = s0; d = d0; j = i; }
  else if (i < n0f + n1f)     { s = s1; d = d1; j = i - n0f; }
  else if (i < n0f + n1f + n2f) { s = s2; d = d2; j = i - n0f - n1f; }
  else return;
  float4 v = reinterpret_cast<const float4*>(s)[j];
  ushort4 o;
  o.x = f2bf(v.x); o.y = f2bf(v.y); o.z = f2bf(v.z); o.w = f2bf(v.w);
  reinterpret_cast<ushort4*>(d)[j] = o;
}

// ---------------- NT GEMM: C[m,n] = sum_k A[m,k]*Bw[n,k] + bias[n] ----------------
// MODE 0: scatter bf16 into Q (b,h,s,d), K (b,h,s,d), V^T (b,h,d,s).
// MODE 1: fp32 store to out.
template<int N, int MODE>
__global__ __launch_bounds__(256, 2)
void gemm_nt(const unsigned short* __restrict__ A,
             const unsigned short* __restrict__ Bw,
             const float* __restrict__ bias,
             unsigned short* __restrict__ qkv_base,
             float* __restrict__ outp)
{
  __shared__ unsigned short As[128*32];
  __shared__ unsigned short Bs[128*32];
  const int tid  = threadIdx.x;
  const int lane = tid & 63;
  const int wid  = tid >> 6;
  const int g = lane >> 4, lr = lane & 15;
  const int wm = wid >> 1, wn = wid & 1;
  const int n0 = blockIdx.x * 128;
  const int m0 = blockIdx.y * 128;

  f32x4 acc[4][4];
  #pragma unroll
  for (int i = 0; i < 4; ++i)
    #pragma unroll
    for (int j = 0; j < 4; ++j) acc[i][j] = f32x4{0.f, 0.f, 0.f, 0.f};

  for (int k0 = 0; k0 < K_; k0 += 32) {
    #pragma unroll
    for (int it = 0; it < 2; ++it) {
      int chunk = tid + it * 256;          // 512 chunks of 8 bf16
      int row = chunk >> 2, slot = chunk & 3;
      int sw = (slot ^ ((row >> 1) & 3)) * 8;
      *reinterpret_cast<uint4*>(&As[row*32 + sw]) =
          *reinterpret_cast<const uint4*>(&A[(size_t)(m0 + row) * K_ + k0 + slot*8]);
      *reinterpret_cast<uint4*>(&Bs[row*32 + sw]) =
          *reinterpret_cast<const uint4*>(&Bw[(size_t)(n0 + row) * K_ + k0 + slot*8]);
    }
    __syncthreads();
    bf16x8 af[4], bfr[4];
    #pragma unroll
    for (int i = 0; i < 4; ++i) {
      int ra = wm*64 + i*16 + lr;
      af[i]  = *reinterpret_cast<const bf16x8*>(&As[ra*32 + ((g ^ ((ra>>1)&3))*8)]);
      int rb = wn*64 + i*16 + lr;
      bfr[i] = *reinterpret_cast<const bf16x8*>(&Bs[rb*32 + ((g ^ ((rb>>1)&3))*8)]);
    }
    #pragma unroll
    for (int i = 0; i < 4; ++i)
      #pragma unroll
      for (int j = 0; j < 4; ++j)
        acc[i][j] = __builtin_amdgcn_mfma_f32_16x16x32_bf16(af[i], bfr[j], acc[i][j], 0, 0, 0);
    __syncthreads();
  }

  // epilogue: C row = m0+wm*64+i*16+g*4+r, col = n0+wn*64+j*16+lr  (m89 layout)
  #pragma unroll
  for (int j = 0; j < 4; ++j) {
    int col = n0 + wn*64 + j*16 + lr;
    float bv = bias[col];
    if constexpr (MODE == 0) {
      int which = col / 768;               // 0=Q 1=K 2=V (frag never crosses boundary)
      int rem = col - which * 768;
      int h = rem >> 6, d = rem & 63;
      if (which < 2) {
        unsigned short* dst = qkv_base + (size_t)which * QKV_ELEMS;
        #pragma unroll
        for (int i = 0; i < 4; ++i)
          #pragma unroll
          for (int r = 0; r < 4; ++r) {
            int rowm = m0 + wm*64 + i*16 + g*4 + r;
            int bb = rowm >> 11, ss = rowm & 2047;
            dst[(((size_t)(bb*NH_ + h))*S_ + ss)*HD_ + d] = f2bf(acc[i][j][r] + bv);
          }
      } else {
        // V stored TRANSPOSED per head: (b,h,d,s); 4 consecutive s -> 8B store
        unsigned short* dst = qkv_base + 2*(size_t)QKV_ELEMS;
        #pragma unroll
        for (int i = 0; i < 4; ++i) {
          int rowm = m0 + wm*64 + i*16 + g*4;
          int bb = rowm >> 11, ss = rowm & 2047;
          unsigned w0 = (unsigned)f2bf(acc[i][j][0] + bv) | ((unsigned)f2bf(acc[i][j][1] + bv) << 16);
          unsigned w1 = (unsigned)f2bf(acc[i][j][2] + bv) | ((unsigned)f2bf(acc[i][j][3] + bv) << 16);
          uint2 u; u.x = w0; u.y = w1;
          *reinterpret_cast<uint2*>(&dst[(((size_t)(bb*NH_ + h))*HD_ + d)*S_ + ss]) = u;
        }
      }
    } else {
      #pragma unroll
      for (int i = 0; i < 4; ++i)
        #pragma unroll
        for (int r = 0; r < 4; ++r) {
          int rowm = m0 + wm*64 + i*16 + g*4 + r;
          outp[(size_t)rowm * H_ + col] = acc[i][j][r] + bv;
        }
    }
  }
}

// ---------------- flash attention (causal), barrier-free streaming ----------------
// Block = 4 waves, one q-tile of 32 rows. Wave w handles kv tiles t === w (mod 4),
// keeping private (m,l,O^T); 4-way merge at the end via LDS (two d-half phases,
// so LDS stays under 20KB). K single-buffered in registers: consumed by QK^T at
// step top, reloaded with tile i+1 immediately after (next use is ~600cyc away).
// All register buffers statically indexed; VGPR peak ~114 -> no scratch.
__global__ __launch_bounds__(256, 4)
void attn_fwd(const unsigned short* __restrict__ Qp,
              const unsigned short* __restrict__ Kp,
              const unsigned short* __restrict__ Vtp,
              unsigned short* __restrict__ attn)
{
  __shared__ float Osc[4][32*36];     // [wave][q*36 + d(0..31)]  (one d-half at a time)
  __shared__ float mlb[4][64];        // [wave][{m[32], l[32]}]

  const int tid = threadIdx.x;
  const int l = tid & 63, w = tid >> 6;
  const int q31 = l & 31, hi = l >> 5;
  // XCD-locked decode: idx%8 == bh%8 (3 heads per XCD -> Q+K+V^T 2.25MB, L2-fits).
  const int idx = blockIdx.x;
  const int bh = (idx & 7) + 8 * ((idx >> 3) % 3);
  const int qo = (idx >> 3) / 3;
  const int qt = 63 - qo;             // heavy q-tiles dispatched first
  const int qrow = qt*32 + q31;

  const unsigned short* Qh  = Qp  + (size_t)bh * S_ * HD_;
  const unsigned short* Kh  = Kp  + (size_t)bh * S_ * HD_;
  const unsigned short* Vth = Vtp + (size_t)bh * HD_ * S_;

  // Q B-frags (col = q31, k = d)
  bf16x8 qf[4];
  #pragma unroll
  for (int ks = 0; ks < 4; ++ks)
    qf[ks] = *reinterpret_cast<const bf16x8*>(&Qh[(size_t)qrow*HD_ + ks*16 + hi*8]);

  f32x16 oacc0, oacc1;
  #pragma unroll
  for (int r = 0; r < 16; ++r) { oacc0[r] = 0.f; oacc1[r] = 0.f; }
  float mrun = -INF_, lrun = 0.f;

  const int p = w;                                   // kv-tile residue (mod 4)
  const int nt = (qt >= p) ? ((qt - p) >> 2) + 1 : 0;
  const bool dw = ((qt & 3) == p);                   // this wave owns the diag tile
  const int ntm1 = nt - 1;

  // per-lane streaming pointers (advance by 128 kv per owned tile)
  const unsigned short* kptr  = Kh  + (size_t)(p*32 + q31)*HD_ + hi*8;
  const unsigned short* vptr0 = Vth + (size_t)q31*S_      + p*32 + hi*8;
  const unsigned short* vptr1 = Vth + (size_t)(32+q31)*S_ + p*32 + hi*8;

  uint4 kb0, kb1, kb2, kb3, vb0, vb1, vb2, vb3;

  if (nt > 0) {
    kb0 = *reinterpret_cast<const uint4*>(kptr);
    kb1 = *reinterpret_cast<const uint4*>(kptr + 16);
    kb2 = *reinterpret_cast<const uint4*>(kptr + 32);
    kb3 = *reinterpret_cast<const uint4*>(kptr + 48);
  }

  for (int i = 0; i < nt; ++i) {
    // V loads for THIS tile (used at step end -> latency self-hides)
    vb0 = *reinterpret_cast<const uint4*>(vptr0);
    vb1 = *reinterpret_cast<const uint4*>(vptr0 + 16);
    vb2 = *reinterpret_cast<const uint4*>(vptr1);
    vb3 = *reinterpret_cast<const uint4*>(vptr1 + 16);
    vptr0 += 128; vptr1 += 128;

    // ---- S^T = K . Q^T (32 kv x 32 q) ----
    f32x16 sf;
    #pragma unroll
    for (int r = 0; r < 16; ++r) sf[r] = 0.f;
    __builtin_amdgcn_s_setprio(1);
    sf = __builtin_amdgcn_mfma_f32_32x32x16_bf16(*reinterpret_cast<bf16x8*>(&kb0), qf[0], sf, 0, 0, 0);
    sf = __builtin_amdgcn_mfma_f32_32x32x16_bf16(*reinterpret_cast<bf16x8*>(&kb1), qf[1], sf, 0, 0, 0);
    sf = __builtin_amdgcn_mfma_f32_32x32x16_bf16(*reinterpret_cast<bf16x8*>(&kb2), qf[2], sf, 0, 0, 0);
    sf = __builtin_amdgcn_mfma_f32_32x32x16_bf16(*reinterpret_cast<bf16x8*>(&kb3), qf[3], sf, 0, 0, 0);
    __builtin_amdgcn_s_setprio(0);

    // K prefetch for NEXT tile into the same regs (QK above already consumed them;
    // next use is after softmax+PV ~600cyc away, covers L2 latency)
    if (i < ntm1) {
      kptr += 128*HD_;
      kb0 = *reinterpret_cast<const uint4*>(kptr);
      kb1 = *reinterpret_cast<const uint4*>(kptr + 16);
      kb2 = *reinterpret_cast<const uint4*>(kptr + 32);
      kb3 = *reinterpret_cast<const uint4*>(kptr + 48);
    }

    // ---- causal mask (diag tile only; it is this wave's last step) ----
    if (dw && i == ntm1) {
      const int kv0 = qt*32;
      #pragma unroll
      for (int r = 0; r < 16; ++r) {
        int kv = kv0 + (r & 3) + 8*(r >> 2) + 4*hi;
        if (kv > qrow) sf[r] = -1e38f;
      }
    }

    // ---- lane-local online softmax (exp2 domain), defer-max (THR=8) ----
    float mtr = sf[0];
    #pragma unroll
    for (int r = 1; r < 16; ++r) mtr = fmaxf(mtr, sf[r]);
    mtr = fmaxf(mtr, __shfl_xor(mtr, 32));
    float mt = mtr * SCL_;
    float corr = 1.f;
    if (__any(mt > mrun + 8.0f)) {
      float mnew = fmaxf(mrun, mt);
      corr = fexp2(mrun - mnew);
      mrun = mnew;
      #pragma unroll
      for (int r = 0; r < 16; ++r) { oacc0[r] *= corr; oacc1[r] *= corr; }
    }
    float rs = 0.f;
    #pragma unroll
    for (int r = 0; r < 16; ++r) {
      sf[r] = fexp2(fmaf(sf[r], SCL_, -mrun));
      rs += sf[r];
    }
    rs += __shfl_xor(rs, 32);
    lrun = fmaf(lrun, corr, rs);

    // ---- P^T B-frags in-register: cvt_pk pairs + permlane32_swap ----
    unsigned pw0 = cvtpk(sf[0],  sf[1]);
    unsigned pw1 = cvtpk(sf[2],  sf[3]);
    unsigned pw2 = cvtpk(sf[4],  sf[5]);
    unsigned pw3 = cvtpk(sf[6],  sf[7]);
    unsigned pw4 = cvtpk(sf[8],  sf[9]);
    unsigned pw5 = cvtpk(sf[10], sf[11]);
    unsigned pw6 = cvtpk(sf[12], sf[13]);
    unsigned pw7 = cvtpk(sf[14], sf[15]);
    asm("v_permlane32_swap_b32 %0, %1" : "+v"(pw0), "+v"(pw2));
    asm("v_permlane32_swap_b32 %0, %1" : "+v"(pw1), "+v"(pw3));
    asm("v_permlane32_swap_b32 %0, %1" : "+v"(pw4), "+v"(pw6));
    asm("v_permlane32_swap_b32 %0, %1" : "+v"(pw5), "+v"(pw7));
    uint4 pf0; pf0.x = pw0; pf0.y = pw1; pf0.z = pw2; pf0.w = pw3;
    uint4 pf1; pf1.x = pw4; pf1.y = pw5; pf1.z = pw6; pf1.w = pw7;

    // ---- O^T += V^T . P^T ----
    __builtin_amdgcn_s_setprio(1);
    oacc0 = __builtin_amdgcn_mfma_f32_32x32x16_bf16(
        *reinterpret_cast<bf16x8*>(&vb0), *reinterpret_cast<bf16x8*>(&pf0), oacc0, 0, 0, 0);
    oacc0 = __builtin_amdgcn_mfma_f32_32x32x16_bf16(
        *reinterpret_cast<bf16x8*>(&vb1), *reinterpret_cast<bf16x8*>(&pf1), oacc0, 0, 0, 0);
    oacc1 = __builtin_amdgcn_mfma_f32_32x32x16_bf16(
        *reinterpret_cast<bf16x8*>(&vb2), *reinterpret_cast<bf16x8*>(&pf0), oacc1, 0, 0, 0);
    oacc1 = __builtin_amdgcn_mfma_f32_32x32x16_bf16(
        *reinterpret_cast<bf16x8*>(&vb3), *reinterpret_cast<bf16x8*>(&pf1), oacc1, 0, 0, 0);
    __builtin_amdgcn_s_setprio(0);
  }

  // ---- 4-way merge in two d-half phases (LDS = 4*32*36*4B = 18.4KB) ----
  const int q = tid & 31, dseg8 = tid >> 5;          // dseg8 in 0..7
  const int bb = bh / NH_, hh = bh % NH_;

  // phase 0: d in [0,32)
  #pragma unroll
  for (int rr = 0; rr < 4; ++rr) {
    f32x4 a;
    #pragma unroll
    for (int e = 0; e < 4; ++e) a[e] = oacc0[4*rr + e];
    *reinterpret_cast<f32x4*>(&Osc[w][q31*36 + 8*rr + 4*hi]) = a;
  }
  if (hi == 0) { mlb[w][q31] = mrun; mlb[w][32 + q31] = lrun; }
  __syncthreads();

  float e0, e1, e2, e3, inv;
  {
    float m0 = mlb[0][q], m1 = mlb[1][q], m2 = mlb[2][q], m3 = mlb[3][q];
    float l0 = mlb[0][32+q], l1 = mlb[1][32+q], l2 = mlb[2][32+q], l3 = mlb[3][32+q];
    float M = fmaxf(fmaxf(m0, m1), fmaxf(m2, m3));
    e0 = fexp2(m0 - M); e1 = fexp2(m1 - M); e2 = fexp2(m2 - M); e3 = fexp2(m3 - M);
    inv = 1.f / (l0*e0 + l1*e1 + l2*e2 + l3*e3);
  }
  if (dseg8 < 4) {
    const int dd = dseg8*8;
    f32x4 a0 = *reinterpret_cast<f32x4*>(&Osc[0][q*36 + dd]);
    f32x4 b0 = *reinterpret_cast<f32x4*>(&Osc[0][q*36 + dd + 4]);
    f32x4 a1 = *reinterpret_cast<f32x4*>(&Osc[1][q*36 + dd]);
    f32x4 b1 = *reinterpret_cast<f32x4*>(&Osc[1][q*36 + dd + 4]);
    f32x4 a2 = *reinterpret_cast<f32x4*>(&Osc[2][q*36 + dd]);
    f32x4 b2 = *reinterpret_cast<f32x4*>(&Osc[2][q*36 + dd + 4]);
    f32x4 a3 = *reinterpret_cast<f32x4*>(&Osc[3][q*36 + dd]);
    f32x4 b3 = *reinterpret_cast<f32x4*>(&Osc[3][q*36 + dd + 4]);
    f32x4 ra, rb;
    #pragma unroll
    for (int e = 0; e < 4; ++e) {
      ra[e] = (a0[e]*e0 + a1[e]*e1 + a2[e]*e2 + a3[e]*e3) * inv;
      rb[e] = (b0[e]*e0 + b1[e]*e1 + b2[e]*e2 + b3[e]*e3) * inv;
    }
    uint4 ov;
    ov.x = cvtpk(ra[0], ra[1]); ov.y = cvtpk(ra[2], ra[3]);
    ov.z = cvtpk(rb[0], rb[1]); ov.w = cvtpk(rb[2], rb[3]);
    *reinterpret_cast<uint4*>(&attn[((size_t)(bb*S_ + qt*32 + q))*H_ + hh*HD_ + dd]) = ov;
  }
  __syncthreads();

  // phase 1: d in [32,64)
  #pragma unroll
  for (int rr = 0; rr < 4; ++rr) {
    f32x4 a;
    #pragma unroll
    for (int e = 0; e < 4; ++e) a[e] = oacc1[4*rr + e];
    *reinterpret_cast<f32x4*>(&Osc[w][q31*36 + 8*rr + 4*hi]) = a;
  }
  __syncthreads();

  if (dseg8 >= 4) {
    const int dd = (dseg8 - 4)*8;
    f32x4 a0 = *reinterpret_cast<f32x4*>(&Osc[0][q*36 + dd]);
    f32x4 b0 = *reinterpret_cast<f32x4*>(&Osc[0][q*36 + dd + 4]);
    f32x4 a1 = *reinterpret_cast<f32x4*>(&Osc[1][q*36 + dd]);
    f32x4 b1 = *reinterpret_cast<f32x4*>(&Osc[1][q*36 + dd + 4]);
    f32x4 a2 = *reinterpret_cast<f32x4*>(&Osc[2][q*36 + dd]);
    f32x4 b2 = *reinterpret_cast<f32x4*>(&Osc[2][q*36 + dd + 4]);
    f32x4 a3 = *reinterpret_cast<f32x4*>(&Osc[3][q*36 + dd]);
    f32x4 b3 = *reinterpret_cast<f32x4*>(&Osc[3][q*36 + dd + 4]);
    f32x4 ra, rb;
    #pragma unroll
    for (int e = 0; e < 4; ++e) {
      ra[e] = (a0[e]*e0 + a1[e]*e1 + a2[e]*e2 + a3[e]*e3) * inv;
      rb[e] = (b0[e]*e0 + b1[e]*e1 + b2[e]*e2 + b3[e]*e3) * inv;
    }
    uint4 ov;
    ov.x = cvtpk(ra[0], ra[1]); ov.y = cvtpk(ra[2], ra[3]);
    ov.z = cvtpk(rb[0], rb[1]); ov.w = cvtpk(rb[2], rb[3]);
    *reinterpret_cast<uint4*>(&attn[((size_t)(bb*S_ + qt*32 + q))*H_ + hh*HD_ + 32 + dd]) = ov;
  }
}

// ---------------- launch ----------------
extern "C" void kernel_launch(void* const* d_in, const int* in_sizes, int n_in,
                              void* d_out, int out_size, void* d_ws, size_t ws_size,
                              hipStream_t stream)
{
  const float* x      = (const float*)d_in[0];
  const float* w_qkv  = (const float*)d_in[1];
  const float* b_qkv  = (const float*)d_in[2];
  const float* w_o    = (const float*)d_in[3];
  const float* b_o    = (const float*)d_in[4];
  float* out = (float*)d_out;

  unsigned short* xb    = (unsigned short*)d_ws;          // 4096x768
  unsigned short* wqkvb = xb    + (size_t)M_ * K_;        // 2304x768
  unsigned short* wob   = wqkvb + (size_t)N_QKV * K_;     // 768x768
  unsigned short* Qw    = wob   + (size_t)H_ * H_;        // (b,h,s,d)
  unsigned short* Kw    = Qw + (size_t)QKV_ELEMS;         // (b,h,s,d)
  unsigned short* Vtw   = Kw + (size_t)QKV_ELEMS;         // (b,h,d,s)  TRANSPOSED
  unsigned short* attn  = Vtw + (size_t)QKV_ELEMS;        // 4096x768

  cast3<<<5376, 256, 0, stream>>>(x, xb, 786432,
                                  w_qkv, wqkvb, 442368,
                                  w_o, wob, 147456);
  gemm_nt<N_QKV, 0><<<dim3(18, 32), 256, 0, stream>>>(xb, wqkvb, b_qkv, Qw, nullptr);
  attn_fwd<<<dim3(1536), 256, 0, stream>>>(Qw, Kw, Vtw, attn);
  gemm_nt<H_, 1><<<dim3(6, 32), 256, 0, stream>>>(attn, wob, b_o, nullptr, out);
}

// Round 6
// 108.117 us; speedup vs baseline: 1.4216x; 1.0333x over previous
//
#include <hip/hip_runtime.h>
#include <stdint.h>

// GPT2 attention fused pipeline, MI355X/gfx950.
// B=2, S=2048, H=768, nh=12, hd=64. fp32 I/O, bf16 internal compute (MFMA).

#define B_   2
#define S_   2048
#define H_   768
#define NH_  12
#define HD_  64
#define M_   4096      // B_*S_
#define K_   768
#define N_QKV 2304
#define QKV_ELEMS (B_*NH_*S_*HD_)   // per tensor (Q or K or V^T)
#define INF_ __builtin_inff()
#define SCL_ 0.18033688f            // (1/sqrt(64)) * log2(e)

using bf16x8 = __attribute__((ext_vector_type(8))) __bf16;
using f32x4  = __attribute__((ext_vector_type(4))) float;
using f32x16 = __attribute__((ext_vector_type(16))) float;

__device__ inline unsigned short f2bf(float f) {
  unsigned int u = __float_as_uint(f);
  u = (u + 0x7FFFu + ((u >> 16) & 1u)) >> 16;   // RNE
  return (unsigned short)u;
}
__device__ inline float fexp2(float x) {        // v_exp_f32 = 2^x
  float r; asm("v_exp_f32 %0, %1" : "=v"(r) : "v"(x)); return r;
}
__device__ inline unsigned cvtpk(float lo, float hi) {
  unsigned r; asm("v_cvt_pk_bf16_f32 %0, %1, %2" : "=v"(r) : "v"(lo), "v"(hi)); return r;
}
// async global->LDS, 16B per lane; lds base must be wave-uniform.
__device__ inline void gload_lds16(const void* g, void* l) {
  __builtin_amdgcn_global_load_lds((const __attribute__((address_space(1))) void*)g,
                                   (__attribute__((address_space(3))) void*)l, 16, 0, 0);
}

// ---------------- cast fp32 -> bf16 (3 tensors in one launch) ----------------
__global__ void cast3(const float* __restrict__ s0, unsigned short* __restrict__ d0, int n0f,
                      const float* __restrict__ s1, unsigned short* __restrict__ d1, int n1f,
                      const float* __restrict__ s2, unsigned short* __restrict__ d2, int n2f) {
  int i = blockIdx.x * blockDim.x + threadIdx.x;
  const float* s; unsigned short* d; int j;
  if (i < n0f)                { s = s0; d = d0; j = i; }
  else if (i < n0f + n1f)     { s = s1; d = d1; j = i - n0f; }
  else if (i < n0f + n1f + n2f) { s = s2; d = d2; j = i - n0f - n1f; }
  else return;
  float4 v = reinterpret_cast<const float4*>(s)[j];
  ushort4 o;
  o.x = f2bf(v.x); o.y = f2bf(v.y); o.z = f2bf(v.z); o.w = f2bf(v.w);
  reinterpret_cast<ushort4*>(d)[j] = o;
}

// ---------------- NT GEMM: C[m,n] = sum_k A[m,k]*Bw[n,k] + bias[n] ----------------
// Staging via global_load_lds (16B/lane, linear LDS both sides).
// MODE 0: scatter bf16 into Q (b,h,s,d), K (b,h,s,d), V^T (b,h,d,s).
// MODE 1: fp32 store to out.
template<int N, int MODE>
__global__ __launch_bounds__(256, 2)
void gemm_nt(const unsigned short* __restrict__ A,
             const unsigned short* __restrict__ Bw,
             const float* __restrict__ bias,
             unsigned short* __restrict__ qkv_base,
             float* __restrict__ outp)
{
  __shared__ unsigned short As[128*32];
  __shared__ unsigned short Bs[128*32];
  const int tid  = threadIdx.x;
  const int lane = tid & 63;
  const int wid  = tid >> 6;
  const int g = lane >> 4, lr = lane & 15;
  const int wm = wid >> 1, wn = wid & 1;
  const int n0 = blockIdx.x * 128;
  const int m0 = blockIdx.y * 128;

  f32x4 acc[4][4];
  #pragma unroll
  for (int i = 0; i < 4; ++i)
    #pragma unroll
    for (int j = 0; j < 4; ++j) acc[i][j] = f32x4{0.f, 0.f, 0.f, 0.f};

  for (int k0 = 0; k0 < K_; k0 += 32) {
    // stage A,B tiles: chunk c (0..511) of 8 bf16; row=c>>2, seg=c&3; LDS linear c*16B
    #pragma unroll
    for (int it = 0; it < 2; ++it) {
      int c = it*256 + wid*64 + lane;
      int row = c >> 2, seg = c & 3;
      int lb = __builtin_amdgcn_readfirstlane((it*256 + wid*64) * 8);  // ushort offset
      gload_lds16(&A [(size_t)(m0 + row) * K_ + k0 + seg*8], &As[lb]);
      gload_lds16(&Bw[(size_t)(n0 + row) * K_ + k0 + seg*8], &Bs[lb]);
    }
    __syncthreads();
    bf16x8 af[4], bfr[4];
    #pragma unroll
    for (int i = 0; i < 4; ++i) {
      int ra = wm*64 + i*16 + lr;
      af[i]  = *reinterpret_cast<const bf16x8*>(&As[ra*32 + g*8]);
      int rb = wn*64 + i*16 + lr;
      bfr[i] = *reinterpret_cast<const bf16x8*>(&Bs[rb*32 + g*8]);
    }
    #pragma unroll
    for (int i = 0; i < 4; ++i)
      #pragma unroll
      for (int j = 0; j < 4; ++j)
        acc[i][j] = __builtin_amdgcn_mfma_f32_16x16x32_bf16(af[i], bfr[j], acc[i][j], 0, 0, 0);
    __syncthreads();
  }

  // epilogue: C row = m0+wm*64+i*16+g*4+r, col = n0+wn*64+j*16+lr  (m89 layout)
  #pragma unroll
  for (int j = 0; j < 4; ++j) {
    int col = n0 + wn*64 + j*16 + lr;
    float bv = bias[col];
    if constexpr (MODE == 0) {
      int which = col / 768;               // 0=Q 1=K 2=V (frag never crosses boundary)
      int rem = col - which * 768;
      int h = rem >> 6, d = rem & 63;
      if (which < 2) {
        unsigned short* dst = qkv_base + (size_t)which * QKV_ELEMS;
        #pragma unroll
        for (int i = 0; i < 4; ++i)
          #pragma unroll
          for (int r = 0; r < 4; ++r) {
            int rowm = m0 + wm*64 + i*16 + g*4 + r;
            int bb = rowm >> 11, ss = rowm & 2047;
            dst[(((size_t)(bb*NH_ + h))*S_ + ss)*HD_ + d] = f2bf(acc[i][j][r] + bv);
          }
      } else {
        // V stored TRANSPOSED per head: (b,h,d,s); 4 consecutive s -> 8B store
        unsigned short* dst = qkv_base + 2*(size_t)QKV_ELEMS;
        #pragma unroll
        for (int i = 0; i < 4; ++i) {
          int rowm = m0 + wm*64 + i*16 + g*4;
          int bb = rowm >> 11, ss = rowm & 2047;
          unsigned w0 = (unsigned)f2bf(acc[i][j][0] + bv) | ((unsigned)f2bf(acc[i][j][1] + bv) << 16);
          unsigned w1 = (unsigned)f2bf(acc[i][j][2] + bv) | ((unsigned)f2bf(acc[i][j][3] + bv) << 16);
          uint2 u; u.x = w0; u.y = w1;
          *reinterpret_cast<uint2*>(&dst[(((size_t)(bb*NH_ + h))*HD_ + d)*S_ + ss]) = u;
        }
      }
    } else {
      #pragma unroll
      for (int i = 0; i < 4; ++i)
        #pragma unroll
        for (int r = 0; r < 4; ++r) {
          int rowm = m0 + wm*64 + i*16 + g*4 + r;
          outp[(size_t)rowm * H_ + col] = acc[i][j][r] + bv;
        }
    }
  }
}

// ---------------- flash attention (causal), barrier-free streaming ----------------
// Block = 4 waves; processes the PAIRED q-tiles (63-pr, pr) -> uniform duration;
// grid 768 = exactly 3 blocks/CU at launch_bounds(256,3), all resident.
// Wave w handles kv tiles t === w (mod 4) with private (m,l,O^T); 4-way LDS merge.
// Main loop 2x-unrolled with disjoint register sets (kbA/kbB, vbA/vbB) so the
// scheduler overlaps QK^T(i+1) with softmax/PV(i). No __syncthreads in the loop.
__global__ __launch_bounds__(256, 3)
void attn_fwd(const unsigned short* __restrict__ Qp,
              const unsigned short* __restrict__ Kp,
              const unsigned short* __restrict__ Vtp,
              unsigned short* __restrict__ attn)
{
  __shared__ float Osc[4][32*36];     // [wave][q*36 + d-half]
  __shared__ float mlb[4][64];        // [wave][{m[32], l[32]}]

  const int tid = threadIdx.x;
  const int l = tid & 63, w = tid >> 6;
  const int q31 = l & 31, hi = l >> 5;
  // XCD-locked decode: idx%8 == bh%8 (3 heads per XCD -> Q+K+V^T 2.25MB, L2-fits).
  const int idx = blockIdx.x;
  const int bh = (idx & 7) + 8 * ((idx >> 3) % 3);
  const int pr = (idx >> 3) / 3;       // 0..31
  const unsigned short* Qh  = Qp  + (size_t)bh * S_ * HD_;
  const unsigned short* Kh  = Kp  + (size_t)bh * S_ * HD_;
  const unsigned short* Vth = Vtp + (size_t)bh * HD_ * S_;
  const int bb = bh / NH_, hh = bh % NH_;

  for (int qi = 0; qi < 2; ++qi) {
    const int qt = qi ? pr : (63 - pr);
    const int qrow = qt*32 + q31;

    // Q B-frags (col = q31, k = d)
    bf16x8 qf[4];
    #pragma unroll
    for (int ks = 0; ks < 4; ++ks)
      qf[ks] = *reinterpret_cast<const bf16x8*>(&Qh[(size_t)qrow*HD_ + ks*16 + hi*8]);

    f32x16 oacc0, oacc1;
    #pragma unroll
    for (int r = 0; r < 16; ++r) { oacc0[r] = 0.f; oacc1[r] = 0.f; }
    float mrun = -INF_, lrun = 0.f;

    const int p = w;                                   // kv-tile residue (mod 4)
    const int nt = (qt >= p) ? ((qt - p) >> 2) + 1 : 0;
    const bool dw = ((qt & 3) == p);                   // this wave owns the diag tile
    const int ntm1 = nt - 1;

    const unsigned short* kptr  = Kh  + (size_t)(p*32 + q31)*HD_ + hi*8;
    const unsigned short* vptr0 = Vth + (size_t)q31*S_      + p*32 + hi*8;
    const unsigned short* vptr1 = Vth + (size_t)(32+q31)*S_ + p*32 + hi*8;

    uint4 ka0, ka1, ka2, ka3, kc0, kc1, kc2, kc3;
    uint4 va0, va1, va2, va3, vc0, vc1, vc2, vc3;

    auto LOADK_A = [&]() {
      ka0 = *reinterpret_cast<const uint4*>(kptr);
      ka1 = *reinterpret_cast<const uint4*>(kptr + 16);
      ka2 = *reinterpret_cast<const uint4*>(kptr + 32);
      ka3 = *reinterpret_cast<const uint4*>(kptr + 48);
      kptr += 128*HD_;
    };
    auto LOADK_B = [&]() {
      kc0 = *reinterpret_cast<const uint4*>(kptr);
      kc1 = *reinterpret_cast<const uint4*>(kptr + 16);
      kc2 = *reinterpret_cast<const uint4*>(kptr + 32);
      kc3 = *reinterpret_cast<const uint4*>(kptr + 48);
      kptr += 128*HD_;
    };
    auto LOADV_A = [&]() {
      va0 = *reinterpret_cast<const uint4*>(vptr0);
      va1 = *reinterpret_cast<const uint4*>(vptr0 + 16);
      va2 = *reinterpret_cast<const uint4*>(vptr1);
      va3 = *reinterpret_cast<const uint4*>(vptr1 + 16);
      vptr0 += 128; vptr1 += 128;
    };
    auto LOADV_B = [&]() {
      vc0 = *reinterpret_cast<const uint4*>(vptr0);
      vc1 = *reinterpret_cast<const uint4*>(vptr0 + 16);
      vc2 = *reinterpret_cast<const uint4*>(vptr1);
      vc3 = *reinterpret_cast<const uint4*>(vptr1 + 16);
      vptr0 += 128; vptr1 += 128;
    };

    auto STEP = [&](uint4& k0, uint4& k1, uint4& k2, uint4& k3,
                    uint4& v0, uint4& v1, uint4& v2, uint4& v3, bool isDiag) {
      // ---- S^T = K . Q^T (32 kv x 32 q) ----
      f32x16 sf;
      #pragma unroll
      for (int r = 0; r < 16; ++r) sf[r] = 0.f;
      __builtin_amdgcn_s_setprio(1);
      sf = __builtin_amdgcn_mfma_f32_32x32x16_bf16(*reinterpret_cast<bf16x8*>(&k0), qf[0], sf, 0, 0, 0);
      sf = __builtin_amdgcn_mfma_f32_32x32x16_bf16(*reinterpret_cast<bf16x8*>(&k1), qf[1], sf, 0, 0, 0);
      sf = __builtin_amdgcn_mfma_f32_32x32x16_bf16(*reinterpret_cast<bf16x8*>(&k2), qf[2], sf, 0, 0, 0);
      sf = __builtin_amdgcn_mfma_f32_32x32x16_bf16(*reinterpret_cast<bf16x8*>(&k3), qf[3], sf, 0, 0, 0);
      __builtin_amdgcn_s_setprio(0);

      if (isDiag) {
        const int kv0 = qt*32;
        #pragma unroll
        for (int r = 0; r < 16; ++r) {
          int kv = kv0 + (r & 3) + 8*(r >> 2) + 4*hi;
          if (kv > qrow) sf[r] = -1e38f;
        }
      }

      // ---- lane-local online softmax (exp2 domain), defer-max (THR=8) ----
      float mtr = sf[0];
      #pragma unroll
      for (int r = 1; r < 16; ++r) mtr = fmaxf(mtr, sf[r]);
      mtr = fmaxf(mtr, __shfl_xor(mtr, 32));
      float mt = mtr * SCL_;
      float corr = 1.f;
      if (__any(mt > mrun + 8.0f)) {
        float mnew = fmaxf(mrun, mt);
        corr = fexp2(mrun - mnew);
        mrun = mnew;
        #pragma unroll
        for (int r = 0; r < 16; ++r) { oacc0[r] *= corr; oacc1[r] *= corr; }
      }
      float rs = 0.f;
      #pragma unroll
      for (int r = 0; r < 16; ++r) {
        sf[r] = fexp2(fmaf(sf[r], SCL_, -mrun));
        rs += sf[r];
      }
      rs += __shfl_xor(rs, 32);
      lrun = fmaf(lrun, corr, rs);

      // ---- P^T B-frags in-register: cvt_pk pairs + permlane32_swap ----
      unsigned pw0 = cvtpk(sf[0],  sf[1]);
      unsigned pw1 = cvtpk(sf[2],  sf[3]);
      unsigned pw2 = cvtpk(sf[4],  sf[5]);
      unsigned pw3 = cvtpk(sf[6],  sf[7]);
      unsigned pw4 = cvtpk(sf[8],  sf[9]);
      unsigned pw5 = cvtpk(sf[10], sf[11]);
      unsigned pw6 = cvtpk(sf[12], sf[13]);
      unsigned pw7 = cvtpk(sf[14], sf[15]);
      asm("v_permlane32_swap_b32 %0, %1" : "+v"(pw0), "+v"(pw2));
      asm("v_permlane32_swap_b32 %0, %1" : "+v"(pw1), "+v"(pw3));
      asm("v_permlane32_swap_b32 %0, %1" : "+v"(pw4), "+v"(pw6));
      asm("v_permlane32_swap_b32 %0, %1" : "+v"(pw5), "+v"(pw7));
      uint4 pf0; pf0.x = pw0; pf0.y = pw1; pf0.z = pw2; pf0.w = pw3;
      uint4 pf1; pf1.x = pw4; pf1.y = pw5; pf1.z = pw6; pf1.w = pw7;

      // ---- O^T += V^T . P^T ----
      __builtin_amdgcn_s_setprio(1);
      oacc0 = __builtin_amdgcn_mfma_f32_32x32x16_bf16(
          *reinterpret_cast<bf16x8*>(&v0), *reinterpret_cast<bf16x8*>(&pf0), oacc0, 0, 0, 0);
      oacc0 = __builtin_amdgcn_mfma_f32_32x32x16_bf16(
          *reinterpret_cast<bf16x8*>(&v1), *reinterpret_cast<bf16x8*>(&pf1), oacc0, 0, 0, 0);
      oacc1 = __builtin_amdgcn_mfma_f32_32x32x16_bf16(
          *reinterpret_cast<bf16x8*>(&v2), *reinterpret_cast<bf16x8*>(&pf0), oacc1, 0, 0, 0);
      oacc1 = __builtin_amdgcn_mfma_f32_32x32x16_bf16(
          *reinterpret_cast<bf16x8*>(&v3), *reinterpret_cast<bf16x8*>(&pf1), oacc1, 0, 0, 0);
      __builtin_amdgcn_s_setprio(0);
    };

    // ---- 2x-unrolled pipelined main loop ----
    if (nt > 0) LOADK_A();
    int i = 0;
    for (; i + 2 <= nt; i += 2) {
      LOADV_A();
      LOADK_B();                                   // used by STEP B (~600cyc away)
      STEP(ka0, ka1, ka2, ka3, va0, va1, va2, va3, dw && (i == ntm1));
      LOADV_B();
      if (i + 2 < nt) LOADK_A();                   // used next pair
      STEP(kc0, kc1, kc2, kc3, vc0, vc1, vc2, vc3, dw && (i + 1 == ntm1));
    }
    if (i < nt) {
      LOADV_A();
      STEP(ka0, ka1, ka2, ka3, va0, va1, va2, va3, dw && (i == ntm1));
    }

    // ---- 4-way merge in two d-half phases ----
    const int q = tid & 31, dseg8 = tid >> 5;
    __syncthreads();   // protect Osc against previous q-tile's readers

    // phase 0: d in [0,32)
    #pragma unroll
    for (int rr = 0; rr < 4; ++rr) {
      f32x4 a;
      #pragma unroll
      for (int e = 0; e < 4; ++e) a[e] = oacc0[4*rr + e];
      *reinterpret_cast<f32x4*>(&Osc[w][q31*36 + 8*rr + 4*hi]) = a;
    }
    if (hi == 0) { mlb[w][q31] = mrun; mlb[w][32 + q31] = lrun; }
    __syncthreads();

    float e0, e1, e2, e3, inv;
    {
      float m0 = mlb[0][q], m1 = mlb[1][q], m2 = mlb[2][q], m3 = mlb[3][q];
      float l0 = mlb[0][32+q], l1 = mlb[1][32+q], l2 = mlb[2][32+q], l3 = mlb[3][32+q];
      float M = fmaxf(fmaxf(m0, m1), fmaxf(m2, m3));
      e0 = fexp2(m0 - M); e1 = fexp2(m1 - M); e2 = fexp2(m2 - M); e3 = fexp2(m3 - M);
      inv = 1.f / (l0*e0 + l1*e1 + l2*e2 + l3*e3);
    }
    if (dseg8 < 4) {
      const int dd = dseg8*8;
      f32x4 a0 = *reinterpret_cast<f32x4*>(&Osc[0][q*36 + dd]);
      f32x4 b0 = *reinterpret_cast<f32x4*>(&Osc[0][q*36 + dd + 4]);
      f32x4 a1 = *reinterpret_cast<f32x4*>(&Osc[1][q*36 + dd]);
      f32x4 b1 = *reinterpret_cast<f32x4*>(&Osc[1][q*36 + dd + 4]);
      f32x4 a2 = *reinterpret_cast<f32x4*>(&Osc[2][q*36 + dd]);
      f32x4 b2 = *reinterpret_cast<f32x4*>(&Osc[2][q*36 + dd + 4]);
      f32x4 a3 = *reinterpret_cast<f32x4*>(&Osc[3][q*36 + dd]);
      f32x4 b3 = *reinterpret_cast<f32x4*>(&Osc[3][q*36 + dd + 4]);
      f32x4 ra, rb;
      #pragma unroll
      for (int e = 0; e < 4; ++e) {
        ra[e] = (a0[e]*e0 + a1[e]*e1 + a2[e]*e2 + a3[e]*e3) * inv;
        rb[e] = (b0[e]*e0 + b1[e]*e1 + b2[e]*e2 + b3[e]*e3) * inv;
      }
      uint4 ov;
      ov.x = cvtpk(ra[0], ra[1]); ov.y = cvtpk(ra[2], ra[3]);
      ov.z = cvtpk(rb[0], rb[1]); ov.w = cvtpk(rb[2], rb[3]);
      *reinterpret_cast<uint4*>(&attn[((size_t)(bb*S_ + qt*32 + q))*H_ + hh*HD_ + dd]) = ov;
    }
    __syncthreads();

    // phase 1: d in [32,64)
    #pragma unroll
    for (int rr = 0; rr < 4; ++rr) {
      f32x4 a;
      #pragma unroll
      for (int e = 0; e < 4; ++e) a[e] = oacc1[4*rr + e];
      *reinterpret_cast<f32x4*>(&Osc[w][q31*36 + 8*rr + 4*hi]) = a;
    }
    __syncthreads();

    if (dseg8 >= 4) {
      const int dd = (dseg8 - 4)*8;
      f32x4 a0 = *reinterpret_cast<f32x4*>(&Osc[0][q*36 + dd]);
      f32x4 b0 = *reinterpret_cast<f32x4*>(&Osc[0][q*36 + dd + 4]);
      f32x4 a1 = *reinterpret_cast<f32x4*>(&Osc[1][q*36 + dd]);
      f32x4 b1 = *reinterpret_cast<f32x4*>(&Osc[1][q*36 + dd + 4]);
      f32x4 a2 = *reinterpret_cast<f32x4*>(&Osc[2][q*36 + dd]);
      f32x4 b2 = *reinterpret_cast<f32x4*>(&Osc[2][q*36 + dd + 4]);
      f32x4 a3 = *reinterpret_cast<f32x4*>(&Osc[3][q*36 + dd]);
      f32x4 b3 = *reinterpret_cast<f32x4*>(&Osc[3][q*36 + dd + 4]);
      f32x4 ra, rb;
      #pragma unroll
      for (int e = 0; e < 4; ++e) {
        ra[e] = (a0[e]*e0 + a1[e]*e1 + a2[e]*e2 + a3[e]*e3) * inv;
        rb[e] = (b0[e]*e0 + b1[e]*e1 + b2[e]*e2 + b3[e]*e3) * inv;
      }
      uint4 ov;
      ov.x = cvtpk(ra[0], ra[1]); ov.y = cvtpk(ra[2], ra[3]);
      ov.z = cvtpk(rb[0], rb[1]); ov.w = cvtpk(rb[2], rb[3]);
      *reinterpret_cast<uint4*>(&attn[((size_t)(bb*S_ + qt*32 + q))*H_ + hh*HD_ + 32 + dd]) = ov;
    }
    __syncthreads();
  }
}

// ---------------- launch ----------------
extern "C" void kernel_launch(void* const* d_in, const int* in_sizes, int n_in,
                              void* d_out, int out_size, void* d_ws, size_t ws_size,
                              hipStream_t stream)
{
  const float* x      = (const float*)d_in[0];
  const float* w_qkv  = (const float*)d_in[1];
  const float* b_qkv  = (const float*)d_in[2];
  const float* w_o    = (const float*)d_in[3];
  const float* b_o    = (const float*)d_in[4];
  float* out = (float*)d_out;

  unsigned short* xb    = (unsigned short*)d_ws;          // 4096x768
  unsigned short* wqkvb = xb    + (size_t)M_ * K_;        // 2304x768
  unsigned short* wob   = wqkvb + (size_t)N_QKV * K_;     // 768x768
  unsigned short* Qw    = wob   + (size_t)H_ * H_;        // (b,h,s,d)
  unsigned short* Kw    = Qw + (size_t)QKV_ELEMS;         // (b,h,s,d)
  unsigned short* Vtw   = Kw + (size_t)QKV_ELEMS;         // (b,h,d,s)  TRANSPOSED
  unsigned short* attn  = Vtw + (size_t)QKV_ELEMS;        // 4096x768

  cast3<<<5376, 256, 0, stream>>>(x, xb, 786432,
                                  w_qkv, wqkvb, 442368,
                                  w_o, wob, 147456);
  gemm_nt<N_QKV, 0><<<dim3(18, 32), 256, 0, stream>>>(xb, wqkvb, b_qkv, Qw, nullptr);
  attn_fwd<<<dim3(768), 256, 0, stream>>>(Qw, Kw, Vtw, attn);
  gemm_nt<H_, 1><<<dim3(6, 32), 256, 0, stream>>>(attn, wob, b_o, nullptr, out);
}